// Round 2
// 631.488 us; speedup vs baseline: 1.0038x; 1.0038x over previous
//
#include <hip/hip_runtime.h>

typedef __attribute__((ext_vector_type(8))) short bf16x8;
typedef __attribute__((ext_vector_type(4))) float f32x4;
typedef __attribute__((ext_vector_type(4))) short s16x4;

#define DEV __device__ __forceinline__

DEV short f2bf(float f) {
  union { float f; unsigned u; } v; v.f = f;
  unsigned r = v.u + 0x7fffu + ((v.u >> 16) & 1u);
  return (short)(r >> 16);
}

// packed fp32x2 -> bf16x2 (hardware v_cvt_pk_bf16_f32 on gfx950, RNE)
DEV int pk2(float a, float b) {
#if defined(__has_builtin) && __has_builtin(__builtin_amdgcn_cvt_pk_bf16_f32)
  auto v = __builtin_amdgcn_cvt_pk_bf16_f32(a, b);
  int r; __builtin_memcpy(&r, &v, 4); return r;
#else
  return (int)(unsigned short)f2bf(a) | ((int)(unsigned short)f2bf(b) << 16);
#endif
}

// async global->LDS 16B: lane i's 16B lands at lbase + i*16
DEV void stage16(const short* g, short* lbase, int lane) {
#if defined(__has_builtin) && __has_builtin(__builtin_amdgcn_global_load_lds)
  (void)lane;
  __builtin_amdgcn_global_load_lds((const __attribute__((address_space(1))) void*)g,
                                   (__attribute__((address_space(3))) void*)lbase, 16, 0, 0);
#else
  *(bf16x8*)(lbase + lane * 8) = *(const bf16x8*)g;
#endif
}

DEV void stage16f(const float* g, float* lbase, int lane) {
#if defined(__has_builtin) && __has_builtin(__builtin_amdgcn_global_load_lds)
  (void)lane;
  __builtin_amdgcn_global_load_lds((const __attribute__((address_space(1))) void*)g,
                                   (__attribute__((address_space(3))) void*)lbase, 16, 0, 0);
#else
  *(float4*)(lbase + lane * 4) = *(const float4*)g;
#endif
}

// ---------------- dual transpose fp32 -> bf16: out[n][k] = bf16(in[k][n]) ----------
// z=0: Wq slice of Wqkv (ld 12288); z=1: Wo (ld 4096). One launch for both.
__global__ __launch_bounds__(256) void prep_w(
    const float* __restrict__ wqkv, const float* __restrict__ wo,
    short* __restrict__ out) {
  __shared__ short tile[64][66];
  int z = blockIdx.z;
  const float* in = z ? wo : wqkv;
  long ld = z ? 4096 : 12288;
  short* o = out + (long)z * 16777216L;
  long k0 = blockIdx.x * 64L, n0 = blockIdx.y * 64L;
  int t = threadIdx.x;
  {
    int kl = t >> 4, nl4 = (t & 15) * 4;
#pragma unroll
    for (int i = 0; i < 4; i++) {
      int k = kl + i * 16;
      float4 v = *(const float4*)(in + (k0 + k) * ld + n0 + nl4);
      int* dst = (int*)&tile[k][nl4];
      dst[0] = pk2(v.x, v.y);
      dst[1] = pk2(v.z, v.w);
    }
  }
  __syncthreads();
  {
    int nl = t >> 4, kl4 = (t & 15) * 4;
#pragma unroll
    for (int i = 0; i < 4; i++) {
      int n = nl + i * 16;
      s16x4 w;
      w.x = tile[kl4 + 0][n]; w.y = tile[kl4 + 1][n];
      w.z = tile[kl4 + 2][n]; w.w = tile[kl4 + 3][n];
      *(s16x4*)(o + (n0 + n) * 4096L + k0 + kl4) = w;
    }
  }
}

// ---------------- cast fp32 -> bf16 (8 elems/thread) + zero the fp32 output -------
__global__ __launch_bounds__(256) void cast_f32_bf16(
    const float* __restrict__ in, short* __restrict__ out, int n8,
    float* __restrict__ zbuf) {
  int i = blockIdx.x * 256 + threadIdx.x;
  if (i >= n8) return;
  float4 a = *(const float4*)(in + (long)i * 8);
  float4 b = *(const float4*)(in + (long)i * 8 + 4);
  union { bf16x8 v; int w[4]; } r;
  r.w[0] = pk2(a.x, a.y); r.w[1] = pk2(a.z, a.w);
  r.w[2] = pk2(b.x, b.y); r.w[3] = pk2(b.z, b.w);
  *(bf16x8*)(out + (long)i * 8) = r.v;
  // zero the 4 MB fp32 output buffer so GEMM2 can atomically accumulate into it
  float4 z4 = make_float4(0.f, 0.f, 0.f, 0.f);
  *(float4*)(zbuf + (long)i * 8) = z4;
  *(float4*)(zbuf + (long)i * 8 + 4) = z4;
}

// ---------------- split-K GEMM, M=256 full tile, N-tile 64, BK=64, DMA staging ----
// A bf16 [256][K]; Bt bf16 [N][K]; Cp fp32 partials [z][256][N].
__global__ __launch_bounds__(512) void gemm_dma(
    const short* __restrict__ A, const short* __restrict__ Bt,
    float* __restrict__ Cp, int N, int K, int Kc) {
  __shared__ short As[32 * 512];
  __shared__ short Bs[8 * 512];
  int t = threadIdx.x;
  int lane = t & 63, wave = t >> 6;
  int quad = lane >> 4, m16 = lane & 15;
  long n0 = blockIdx.x * 64L;
  int z = blockIdx.y;
  f32x4 acc[2][4] = {};
  int kbeg = z * Kc, kend = kbeg + Kc;

  for (int k0 = kbeg; k0 < kend; k0 += 64) {
    __syncthreads();
#pragma unroll
    for (int i = 0; i < 2; i++)
#pragma unroll
      for (int s = 0; s < 2; s++) {
        int row = (2 * wave + i) * 16 + m16;
        const short* g = A + (long)row * K + k0 + (s * 4 + quad) * 8;
        stage16(g, &As[(4 * wave + 2 * i + s) * 512], lane);
      }
    {
      int nt = wave >> 1, s = wave & 1;
      long row = n0 + nt * 16 + m16;
      const short* g = Bt + row * (long)K + k0 + (s * 4 + quad) * 8;
      stage16(g, &Bs[wave * 512], lane);
    }
    __syncthreads();
#pragma unroll
    for (int s = 0; s < 2; s++) {
      bf16x8 a0 = *(bf16x8*)&As[(4 * wave + s) * 512 + lane * 8];
      bf16x8 a1 = *(bf16x8*)&As[(4 * wave + 2 + s) * 512 + lane * 8];
#pragma unroll
      for (int nt = 0; nt < 4; nt++) {
        bf16x8 b = *(bf16x8*)&Bs[(nt * 2 + s) * 512 + lane * 8];
        acc[0][nt] = __builtin_amdgcn_mfma_f32_16x16x32_bf16(a0, b, acc[0][nt], 0, 0, 0);
        acc[1][nt] = __builtin_amdgcn_mfma_f32_16x16x32_bf16(a1, b, acc[1][nt], 0, 0, 0);
      }
    }
  }
  float* C = Cp + (long)z * 256 * N;
#pragma unroll
  for (int i = 0; i < 2; i++)
#pragma unroll
    for (int nt = 0; nt < 4; nt++)
#pragma unroll
      for (int rg = 0; rg < 4; rg++) {
        long m = (2 * wave + i) * 16 + quad * 4 + rg;
        C[m * (long)N + n0 + nt * 16 + m16] = acc[i][nt][rg];
      }
}

// ---------------- same GEMM but split-K blocks accumulate straight into C --------
__global__ __launch_bounds__(512) void gemm_dma_atomic(
    const short* __restrict__ A, const short* __restrict__ Bt,
    float* __restrict__ C, int N, int K, int Kc) {
  __shared__ short As[32 * 512];
  __shared__ short Bs[8 * 512];
  int t = threadIdx.x;
  int lane = t & 63, wave = t >> 6;
  int quad = lane >> 4, m16 = lane & 15;
  long n0 = blockIdx.x * 64L;
  int z = blockIdx.y;
  f32x4 acc[2][4] = {};
  int kbeg = z * Kc, kend = kbeg + Kc;

  for (int k0 = kbeg; k0 < kend; k0 += 64) {
    __syncthreads();
#pragma unroll
    for (int i = 0; i < 2; i++)
#pragma unroll
      for (int s = 0; s < 2; s++) {
        int row = (2 * wave + i) * 16 + m16;
        const short* g = A + (long)row * K + k0 + (s * 4 + quad) * 8;
        stage16(g, &As[(4 * wave + 2 * i + s) * 512], lane);
      }
    {
      int nt = wave >> 1, s = wave & 1;
      long row = n0 + nt * 16 + m16;
      const short* g = Bt + row * (long)K + k0 + (s * 4 + quad) * 8;
      stage16(g, &Bs[wave * 512], lane);
    }
    __syncthreads();
#pragma unroll
    for (int s = 0; s < 2; s++) {
      bf16x8 a0 = *(bf16x8*)&As[(4 * wave + s) * 512 + lane * 8];
      bf16x8 a1 = *(bf16x8*)&As[(4 * wave + 2 + s) * 512 + lane * 8];
#pragma unroll
      for (int nt = 0; nt < 4; nt++) {
        bf16x8 b = *(bf16x8*)&Bs[(nt * 2 + s) * 512 + lane * 8];
        acc[0][nt] = __builtin_amdgcn_mfma_f32_16x16x32_bf16(a0, b, acc[0][nt], 0, 0, 0);
        acc[1][nt] = __builtin_amdgcn_mfma_f32_16x16x32_bf16(a1, b, acc[1][nt], 0, 0, 0);
      }
    }
  }
#pragma unroll
  for (int i = 0; i < 2; i++)
#pragma unroll
    for (int nt = 0; nt < 4; nt++)
#pragma unroll
      for (int rg = 0; rg < 4; rg++) {
        long m = (2 * wave + i) * 16 + quad * 4 + rg;
        unsafeAtomicAdd(&C[m * (long)N + n0 + nt * 16 + m16], acc[i][nt][rg]);
      }
}

// ---------------- double RMSNorm + RoPE + scale on Q (sums 8 K-split partials) ----
__global__ __launch_bounds__(256) void q_norm_rope(
    const float* __restrict__ qtmp, const float* __restrict__ qw,
    const float* __restrict__ cosp, const float* __restrict__ sinp,
    short* __restrict__ qr) {
  int wid = blockIdx.x * 4 + (threadIdx.x >> 6);
  int lane = threadIdx.x & 63;
  int rrow = wid >> 5, h = wid & 31;
  long base = (long)rrow * 4096 + h * 128;
  const long STR = 256L * 4096;
  float x1 = 0.f, x2 = 0.f;
#pragma unroll
  for (int z = 0; z < 8; z++) {
    x1 += qtmp[z * STR + base + lane];
    x2 += qtmp[z * STR + base + 64 + lane];
  }
  float w1 = qw[lane], w2 = qw[64 + lane];
  float ss = x1 * x1 + x2 * x2;
#pragma unroll
  for (int m = 1; m < 64; m <<= 1) ss += __shfl_xor(ss, m, 64);
  float rs = rsqrtf(ss * (1.0f / 128.0f) + 1e-6f);
  float y1 = x1 * rs * w1, y2 = x2 * rs * w2;
  float ss2 = y1 * y1 + y2 * y2;
#pragma unroll
  for (int m = 1; m < 64; m <<= 1) ss2 += __shfl_xor(ss2, m, 64);
  float rs2 = rsqrtf(ss2 * (1.0f / 128.0f) + 1e-6f);
  float z1 = y1 * rs2 * w1, z2 = y2 * rs2 * w2;
  long cpos = (long)(4096 + (rrow & 63)) * 128;
  float c1 = cosp[cpos + lane], c2 = cosp[cpos + 64 + lane];
  float s1 = sinp[cpos + lane], s2 = sinp[cpos + 64 + lane];
  const float scale = 0.08838834764831845f;  // 1/sqrt(128)
  float o1 = (z1 * c1 - z2 * s1) * scale;
  float o2 = (z2 * c2 + z1 * s2) * scale;
  qr[base + lane] = f2bf(o1);
  qr[base + 64 + lane] = f2bf(o2);
}

// ---------------- flash attention, split-K over key dim ----------------
// v2: 7 splits of up to 10 tiles (last split 5); next-tile K/V rows are
// DMA-prefetched into Xraw (fp32, chunk-XOR-swizzled) during the compute phase.
#define ATT_SPLIT 7
#define ATT_TILES 10

__global__ __launch_bounds__(256) void attn_kernel(
    const short* __restrict__ qr, const float* __restrict__ th,
    const float* __restrict__ hs, const float* __restrict__ cosp,
    const float* __restrict__ sinp, float* __restrict__ part,
    float* __restrict__ mstat, float* __restrict__ lstat) {
  __shared__ short Ks[64 * 136];   // roped K, [l][d], pad 136
  __shared__ short Vt[128 * 80];   // raw V transposed, [d][l^swz], pad 80
  __shared__ short Ps[64 * 72];    // P (C-layout -> A-layout round trip)
  __shared__ float Xraw[64 * 128]; // raw fp32 K/V rows (next tile), chunk-XOR swz
  int bh = blockIdx.x, split = blockIdx.y;
  int b = bh >> 5, h = bh & 31;
  int t = threadIdx.x;
  int wave = t >> 6, lane = t & 63, quad = lane >> 4, m16 = lane & 15;

  int tile0 = split * ATT_TILES;            // global 64-key tile index base
  int ntiles = (65 - tile0 < ATT_TILES) ? (65 - tile0) : ATT_TILES;

  bf16x8 aq[4];
  {
    const short* qrow = qr + (long)(b * 64 + wave * 16 + m16) * 4096 + h * 128;
#pragma unroll
    for (int s = 0; s < 4; s++) aq[s] = *(const bf16x8*)(qrow + s * 32 + quad * 8);
  }
  float mi[4] = {-INFINITY, -INFINITY, -INFINITY, -INFINITY};
  float li[4] = {0.f, 0.f, 0.f, 0.f};
  f32x4 oacc[8] = {};

  int srow = t >> 2;  // staging: 4 threads per key-row
  int sc = t & 3;
  int colw = srow ^ (sc * 16);  // XOR swizzle for Vt writes

  // --- prologue: DMA tile0's 64 rows x 128 floats into Xraw ---
  // wave w, inst j covers rows (w*8+j)*2 .. +1; lane covers 16B slot cs = lane&31
  // of row r; slot cs holds source chunk cs ^ (r&7)  (bank-conflict-free reads).
  {
    int tl = tile0;
#pragma unroll
    for (int j = 0; j < 8; j++) {
      int r = (wave * 8 + j) * 2 + (lane >> 5);
      int lgn = tl * 64 + r;
      int cs = lane & 31;
      int fo = (cs ^ (r & 7)) << 2;
      const float* src = (lgn < 4096)
          ? th + ((long)b * 4096 + lgn) * 4096 + h * 128 + fo
          : hs + ((long)b * 64 + (lgn - 4096)) * 4096 + h * 128 + fo;
      stage16f(src, &Xraw[(wave * 8 + j) * 256], lane);
    }
  }

  for (int tt = 0; tt < ntiles; tt++) {
    int lg = (tile0 + tt) * 64 + srow;
    __syncthreads();  // drains DMA (vmcnt0) + prev compute's LDS reads
    {
      const float* crow = cosp + (long)lg * 128;
      const float* srw = sinp + (long)lg * 128;
      const float* xrow = Xraw + srow * 128;
      int sx = srow & 7;
#pragma unroll
      for (int i = 0; i < 2; i++) {
        int c = sc + 4 * i;
        int d1 = c * 8, d2 = d1 + 64;
        int c0 = c * 2;  // 16B-chunk index of d1
        alignas(16) float xa[8], xb[8], cA[8], sA[8], cB[8], sB[8];
        *(float4*)&xa[0] = *(const float4*)(xrow + ((c0 ^ sx) << 2));
        *(float4*)&xa[4] = *(const float4*)(xrow + (((c0 + 1) ^ sx) << 2));
        *(float4*)&xb[0] = *(const float4*)(xrow + (((c0 + 16) ^ sx) << 2));
        *(float4*)&xb[4] = *(const float4*)(xrow + (((c0 + 17) ^ sx) << 2));
        *(float4*)&cA[0] = *(const float4*)(crow + d1);
        *(float4*)&cA[4] = *(const float4*)(crow + d1 + 4);
        *(float4*)&cB[0] = *(const float4*)(crow + d2);
        *(float4*)&cB[4] = *(const float4*)(crow + d2 + 4);
        *(float4*)&sA[0] = *(const float4*)(srw + d1);
        *(float4*)&sA[4] = *(const float4*)(srw + d1 + 4);
        *(float4*)&sB[0] = *(const float4*)(srw + d2);
        *(float4*)&sB[4] = *(const float4*)(srw + d2 + 4);
        union { bf16x8 v; int w[4]; } K1, K2;
#pragma unroll
        for (int jj = 0; jj < 4; jj++) {
          int j0 = 2 * jj, j1 = 2 * jj + 1;
          K1.w[jj] = pk2(xa[j0] * cA[j0] - xb[j0] * sA[j0],
                         xa[j1] * cA[j1] - xb[j1] * sA[j1]);
          K2.w[jj] = pk2(xb[j0] * cB[j0] + xa[j0] * sB[j0],
                         xb[j1] * cB[j1] + xa[j1] * sB[j1]);
        }
        *(bf16x8*)&Ks[srow * 136 + d1] = K1.v;
        *(bf16x8*)&Ks[srow * 136 + d2] = K2.v;
#pragma unroll
        for (int jj = 0; jj < 4; jj++) {
          int p1 = pk2(xa[2 * jj], xa[2 * jj + 1]);
          int p2 = pk2(xb[2 * jj], xb[2 * jj + 1]);
          Vt[(d1 + 2 * jj) * 80 + colw] = (short)(p1 & 0xffff);
          Vt[(d1 + 2 * jj + 1) * 80 + colw] = (short)((unsigned)p1 >> 16);
          Vt[(d2 + 2 * jj) * 80 + colw] = (short)(p2 & 0xffff);
          Vt[(d2 + 2 * jj + 1) * 80 + colw] = (short)((unsigned)p2 >> 16);
        }
      }
    }
    __syncthreads();  // staging visible; all Xraw reads drained

    // issue next tile's DMA now; its latency hides under QK/softmax/PV,
    // and the loop-top barrier's vmcnt(0) drain guarantees arrival.
    if (tt + 1 < ntiles) {
      int tl = tile0 + tt + 1;
#pragma unroll
      for (int j = 0; j < 8; j++) {
        int r = (wave * 8 + j) * 2 + (lane >> 5);
        int lgn = tl * 64 + r;
        int cs = lane & 31;
        int fo = (cs ^ (r & 7)) << 2;
        const float* src = (lgn < 4096)
            ? th + ((long)b * 4096 + lgn) * 4096 + h * 128 + fo
            : hs + ((long)b * 64 + (lgn - 4096)) * 4096 + h * 128 + fo;
        stage16f(src, &Xraw[(wave * 8 + j) * 256], lane);
      }
    }

    // S = Q K^T
    f32x4 sacc[4] = {};
#pragma unroll
    for (int s = 0; s < 4; s++)
#pragma unroll
      for (int nt = 0; nt < 4; nt++) {
        bf16x8 bk = *(const bf16x8*)&Ks[(nt * 16 + m16) * 136 + s * 32 + quad * 8];
        sacc[nt] = __builtin_amdgcn_mfma_f32_16x16x32_bf16(aq[s], bk, sacc[nt], 0, 0, 0);
      }

    // online softmax (rows are wave-private)
    float mnew[4], alpha[4];
#pragma unroll
    for (int rg = 0; rg < 4; rg++) {
      float mx = fmaxf(fmaxf(sacc[0][rg], sacc[1][rg]), fmaxf(sacc[2][rg], sacc[3][rg]));
#pragma unroll
      for (int msk = 1; msk < 16; msk <<= 1) mx = fmaxf(mx, __shfl_xor(mx, msk, 16));
      mnew[rg] = fmaxf(mi[rg], mx);
      alpha[rg] = __expf(mi[rg] - mnew[rg]);
      mi[rg] = mnew[rg];
    }
#pragma unroll
    for (int rg = 0; rg < 4; rg++) {
      float rs = 0.f;
#pragma unroll
      for (int nt = 0; nt < 4; nt++) {
        float p = __expf(sacc[nt][rg] - mnew[rg]);
        rs += p;
        Ps[(wave * 16 + quad * 4 + rg) * 72 + nt * 16 + m16] = f2bf(p);
      }
#pragma unroll
      for (int msk = 1; msk < 16; msk <<= 1) rs += __shfl_xor(rs, msk, 16);
      li[rg] = li[rg] * alpha[rg] + rs;
    }
#pragma unroll
    for (int nt = 0; nt < 8; nt++) {
      f32x4 o = oacc[nt];
      o[0] *= alpha[0]; o[1] *= alpha[1]; o[2] *= alpha[2]; o[3] *= alpha[3];
      oacc[nt] = o;
    }

    // O += P V
    bf16x8 ap[2];
#pragma unroll
    for (int s = 0; s < 2; s++)
      ap[s] = *(const bf16x8*)&Ps[(wave * 16 + m16) * 72 + s * 32 + quad * 8];
#pragma unroll
    for (int s = 0; s < 2; s++)
#pragma unroll
      for (int nt = 0; nt < 8; nt++) {
        int d16 = nt * 16 + m16;
        int scd = (d16 >> 3) & 3;
        int cb = (s * 32 + quad * 8) ^ (scd * 16);
        bf16x8 bv = *(const bf16x8*)&Vt[d16 * 80 + cb];
        oacc[nt] = __builtin_amdgcn_mfma_f32_16x16x32_bf16(ap[s], bv, oacc[nt], 0, 0, 0);
      }
  }

  long pbase = (long)(bh * ATT_SPLIT + split) * 64;
#pragma unroll
  for (int nt = 0; nt < 8; nt++)
#pragma unroll
    for (int rg = 0; rg < 4; rg++)
      part[(pbase + wave * 16 + quad * 4 + rg) * 128 + nt * 16 + m16] = oacc[nt][rg];
  if (m16 == 0)
#pragma unroll
    for (int rg = 0; rg < 4; rg++) {
      mstat[pbase + wave * 16 + quad * 4 + rg] = mi[rg];
      lstat[pbase + wave * 16 + quad * 4 + rg] = li[rg];
    }
}

// ---------------- merge the splits ----------------
__global__ __launch_bounds__(128) void attn_merge(
    const float* __restrict__ part, const float* __restrict__ mstat,
    const float* __restrict__ lstat, short* __restrict__ attn) {
  int idx = blockIdx.x;  // bh*64 + q
  int bh = idx >> 6, q = idx & 63;
  int d = threadIdx.x;
  float mstar = -INFINITY;
#pragma unroll
  for (int s = 0; s < ATT_SPLIT; s++)
    mstar = fmaxf(mstar, mstat[((long)bh * ATT_SPLIT + s) * 64 + q]);
  float denom = 0.f, o = 0.f;
#pragma unroll
  for (int s = 0; s < ATT_SPLIT; s++) {
    long sq = ((long)bh * ATT_SPLIT + s) * 64 + q;
    float w = __expf(mstat[sq] - mstar);
    denom += w * lstat[sq];
    o += w * part[sq * 128 + d];
  }
  int b = bh >> 5, h = bh & 31;
  attn[(long)(b * 64 + q) * 4096 + h * 128 + d] = f2bf(o / denom);
}

extern "C" void kernel_launch(void* const* d_in, const int* in_sizes, int n_in,
                              void* d_out, int out_size, void* d_ws, size_t ws_size,
                              hipStream_t stream) {
  const float* hs = (const float*)d_in[0];     // (4,64,4096)
  const float* th = (const float*)d_in[1];     // (4,4096,4096)
  const float* cosp = (const float*)d_in[2];   // (4160,128)
  const float* sinp = (const float*)d_in[3];
  const float* wqkv = (const float*)d_in[4];   // (4096,12288)
  const float* wo = (const float*)d_in[5];     // (4096,4096)
  const float* qw = (const float*)d_in[6];     // (128,)
  float* out = (float*)d_out;                  // (4,64,4096) fp32

  char* ws = (char*)d_ws;
  short* WT   = (short*)ws;                      // 64 MB: Wq^T | Wo^T
  short* hsb  = (short*)(ws + (64L << 20));      // 2 MB  bf16 hidden_states
  float* qtmp = (float*)(ws + (66L << 20));      // 32 MB (8 split-K partials)
  short* qrb  = (short*)(ws + (98L << 20));      // 2 MB
  short* attnb= (short*)(ws + (100L << 20));     // 2 MB
  float* part = (float*)(ws + (102L << 20));     // 28 MB (7 splits)
  float* mstat= (float*)(ws + (131L << 20));     // 229 KB
  float* lstat= (float*)(ws + (132L << 20));     // 229 KB

  // 1) Wq^T and Wo^T in one launch
  prep_w<<<dim3(64, 64, 2), 256, 0, stream>>>(wqkv, wo, WT);
  // 2) hs -> bf16, and zero `out` for GEMM2's atomic accumulation
  cast_f32_bf16<<<512, 256, 0, stream>>>(hs, hsb, 131072, out);
  // 3) Q partials = hs @ Wq (8-way split-K, DMA-staged MFMA)
  gemm_dma<<<dim3(64, 8), 512, 0, stream>>>(hsb, WT, qtmp, 4096, 4096, 512);
  // 4) sum partials + double RMSNorm + RoPE + 1/sqrt(D)
  q_norm_rope<<<2048, 256, 0, stream>>>(qtmp, qw, cosp, sinp, qrb);
  // 5) flash attention, 7-way key split with DMA tile prefetch
  attn_kernel<<<dim3(128, ATT_SPLIT), 256, 0, stream>>>(qrb, th, hs, cosp, sinp,
                                                        part, mstat, lstat);
  // 6) merge splits
  attn_merge<<<128 * 64, 128, 0, stream>>>(part, mstat, lstat, attnb);
  // 7) out += attn @ Wo (8-way split-K, atomic fp32 accumulate)
  gemm_dma_atomic<<<dim3(64, 8), 512, 0, stream>>>(attnb, WT + 16777216L, out,
                                                   4096, 4096, 512);
}